// Round 3
// baseline (543.097 us; speedup 1.0000x reference)
//
#include <hip/hip_runtime.h>

// BitLinear: out[b,t,o] = scale_x[b,t] * scale_w * sum_d qx[b,t,d] * tw[o,d]
// qx = clip(round(127*x/(max|x|row + eps)), -128, 127)   (int8, exact)
// tw = clip(round(w/(mean|W| + eps)), -1, 1)             (ternary, exact)
// Integer GEMM via mfma_i32_16x16x64_i8, fp32 dequant epilogue.
// R3: minimum-LDS-traffic phase plan (48 ds_read/wave/iter, was 56):
// hold both A halves + both B quadrants in regs; reads only in p1/p2 (p5/p6),
// pure-MFMA p3/p4 (p7/p8). Stage/gate ledger re-derived (VM6 at p4/p8).

#define M_ROWS 4096   // B*T
#define K_DIM  4096   // D_IN
#define N_DIM  16384  // D_OUT
#define W_ELEMS (N_DIM * K_DIM)          // 67108864
#define EPSF 1e-8f

using i32x4 = __attribute__((ext_vector_type(4))) int;

// ---------- kernel 1: |W| partial sums (deterministic) ----------
__global__ void k_abs_partial(const float4* __restrict__ w4,
                              double* __restrict__ part) {
    const int tid = threadIdx.x;
    int idx = blockIdx.x * 256 + tid;
    double s = 0.0;
    #pragma unroll 4
    for (int it = 0; it < 32; ++it) {
        float4 v = w4[idx + it * (2048 * 256)];
        s += (double)fabsf(v.x) + (double)fabsf(v.y)
           + (double)fabsf(v.z) + (double)fabsf(v.w);
    }
    __shared__ double red[256];
    red[tid] = s;
    __syncthreads();
    for (int o = 128; o > 0; o >>= 1) {
        if (tid < o) red[tid] += red[tid + o];
        __syncthreads();
    }
    if (tid == 0) part[blockIdx.x] = red[0];
}

__global__ void k_abs_final(const double* __restrict__ part,
                            float* __restrict__ scales) {
    const int tid = threadIdx.x;
    double s = 0.0;
    #pragma unroll
    for (int k = 0; k < 8; ++k) s += part[tid + k * 256];
    __shared__ double red[256];
    red[tid] = s;
    __syncthreads();
    for (int o = 128; o > 0; o >>= 1) {
        if (tid < o) red[tid] += red[tid + o];
        __syncthreads();
    }
    if (tid == 0) {
        float sw = (float)(red[0] / (double)W_ELEMS);
        scales[0] = sw;
        scales[1] = sw + EPSF;
    }
}

// ---------- kernel 2: ternary weight quant ----------
__global__ void k_wquant(const float4* __restrict__ w4,
                         const float* __restrict__ scales,
                         char4* __restrict__ wq4) {
    const float seps = scales[1];
    int idx = blockIdx.x * 256 + threadIdx.x;
    const int stride = 8192 * 256;
    #pragma unroll
    for (int it = 0; it < 8; ++it) {
        int i = idx + it * stride;
        float4 v = w4[i];
        char4 q;
        q.x = (signed char)(int)fminf(fmaxf(rintf(v.x / seps), -1.0f), 1.0f);
        q.y = (signed char)(int)fminf(fmaxf(rintf(v.y / seps), -1.0f), 1.0f);
        q.z = (signed char)(int)fminf(fmaxf(rintf(v.z / seps), -1.0f), 1.0f);
        q.w = (signed char)(int)fminf(fmaxf(rintf(v.w / seps), -1.0f), 1.0f);
        wq4[i] = q;
    }
}

// ---------- kernel 3: per-token int8 activation quant ----------
__global__ void k_xquant(const float4* __restrict__ x4,
                         char4* __restrict__ xq4,
                         float* __restrict__ sx) {
    const int row = blockIdx.x, tid = threadIdx.x;
    const float4* xr = x4 + (size_t)row * (K_DIM / 4);
    float4 v[4];
    float m = 0.0f;
    #pragma unroll
    for (int j = 0; j < 4; ++j) {
        v[j] = xr[tid + j * 256];
        m = fmaxf(m, fmaxf(fmaxf(fabsf(v[j].x), fabsf(v[j].y)),
                           fmaxf(fabsf(v[j].z), fabsf(v[j].w))));
    }
    __shared__ float red[256];
    red[tid] = m;
    __syncthreads();
    for (int o = 128; o > 0; o >>= 1) {
        if (tid < o) red[tid] = fmaxf(red[tid], red[tid + o]);
        __syncthreads();
    }
    const float gamma = red[0];
    const float ge = gamma + EPSF;
    char4* out = xq4 + (size_t)row * (K_DIM / 4);
    #pragma unroll
    for (int j = 0; j < 4; ++j) {
        char4 q;
        q.x = (signed char)(int)fminf(fmaxf(rintf(127.0f * v[j].x / ge), -128.0f), 127.0f);
        q.y = (signed char)(int)fminf(fmaxf(rintf(127.0f * v[j].y / ge), -128.0f), 127.0f);
        q.z = (signed char)(int)fminf(fmaxf(rintf(127.0f * v[j].z / ge), -128.0f), 127.0f);
        q.w = (signed char)(int)fminf(fmaxf(rintf(127.0f * v[j].w / ge), -128.0f), 127.0f);
        out[tid + j * 256] = q;
    }
    if (tid == 0) sx[row] = gamma / 127.0f;
}

// ---------- kernel 4: int8 GEMM, 256x256 tile, 8-phase schedule ----------
__device__ __forceinline__ void gload16(const signed char* g, signed char* l) {
    __builtin_amdgcn_global_load_lds(
        (const __attribute__((address_space(1))) void*)g,
        (__attribute__((address_space(3))) void*)l, 16, 0, 0);
}

#define BAR()   __builtin_amdgcn_s_barrier()
#define LGKM0() asm volatile("s_waitcnt lgkmcnt(0)" ::: "memory")
#define VM6()   asm volatile("s_waitcnt vmcnt(6)" ::: "memory")
#define PRIO1() __builtin_amdgcn_s_setprio(1)
#define PRIO0() __builtin_amdgcn_s_setprio(0)

// Geometry: BM=BN=256, BK=128 i8, 8 waves (2M x 4N), per-wave 128x64 out.
// LDS 128 KiB: 2 dbuf x (A 32K + B 32K), [256 rows][128 B], chunk-XOR swizzle
// LDS[row][c] = G[row][c ^ (row&7)] via pre-swizzled global source (rule #21).
//
// Phase ledger (iter t; k1=2t+1, k2=2t+2, k3=2t+3):
//   p1: rd{bf0,af0}(buf0)  stg A1.mh1(k1)   mma(0,0)
//   p2: rd{bf1,af1}(buf0)  stg B0.nh0(k2)   mma(0,1)
//   p3: --                 stg B0.nh1(k2)   mma(1,1)
//   p4: --                 stg A0.mh0(k2)   mma(1,0)   VM6
//   p5: rd{bf0,af0}(buf1)  stg A0.mh1(k2)   mma(0,0)
//   p6: rd{bf1,af1}(buf1)  stg B1.nh0(k3)   mma(0,1)
//   p7: --                 stg B1.nh1(k3)   mma(1,1)
//   p8: --                 stg A1.mh0(k3)   mma(1,0)   VM6
// Gates (hand-checked): at each VM6 the outstanding count is 14 loads; the
// drained 8 are exactly the regions read in the following two phases.
// Overwrite-safety: every region's last read is >=1 barrier before re-stage.
__global__ __launch_bounds__(512, 2)
void k_gemm8(const signed char* __restrict__ Aq,   // [4096][4096]  (M x K)
             const signed char* __restrict__ Bq,   // [16384][4096] (N x K)
             const float* __restrict__ sx,
             const float* __restrict__ scales,
             float* __restrict__ C) {
    __shared__ __align__(16) signed char lds[131072];

    const int tid  = threadIdx.x;
    const int lane = tid & 63;
    const int wid  = tid >> 6;
    const int l15  = lane & 15;
    const int qg   = lane >> 4;
    const int swz  = l15 & 7;

    // XCD-bijective swizzle (nwg=1024 % 8 == 0) + supergroup-of-8-pm mapping
    const int bid = blockIdx.x;
    const int wg  = (bid & 7) * 128 + (bid >> 3);
    const int gidx   = wg >> 9;
    const int within = wg & 511;
    const int pm = gidx * 8 + (within & 7);   // [0,16)
    const int pn = within >> 3;               // [0,64)

    const int wm = (wid >> 2) * 128;
    const int wn = (wid & 3) * 64;

    // staging: per-lane pre-swizzled source offset (lane l covers row r0+(l>>3),
    // chunk l&7 -> source chunk (l&7)^(l>>3))
    const int l3 = lane >> 3, l7 = lane & 7;
    const int lane_off = l3 * K_DIM + ((l7 ^ l3) << 4);
    const signed char* Asrc = Aq + (size_t)(pm * 256) * K_DIM + lane_off;
    const signed char* Bsrc = Bq + (size_t)(pn * 256) * K_DIM + lane_off;
    const int ar0 = wid * 8;
    const int br0 = (wid >> 2) * 64 + (wid & 3) * 8;

    auto stageA = [&](int buf, int mh, int kt) {
        const int r0 = mh * 64 + ar0;
        const signed char* s = Asrc + (size_t)r0 * K_DIM + kt * 128;
        signed char* d = lds + buf * 65536 + r0 * 128;
        gload16(s, d);
        gload16(s + (size_t)128 * K_DIM, d + 128 * 128);
    };
    auto stageB = [&](int buf, int nh, int kt) {
        const int r0 = nh * 32 + br0;
        const signed char* s = Bsrc + (size_t)r0 * K_DIM + kt * 128;
        signed char* d = lds + buf * 65536 + 32768 + r0 * 128;
        gload16(s, d);
        gload16(s + (size_t)128 * K_DIM, d + 128 * 128);
    };

    i32x4 acc[8][4];
    #pragma unroll
    for (int a = 0; a < 8; ++a)
        #pragma unroll
        for (int b = 0; b < 4; ++b)
            acc[a][b] = (i32x4){0, 0, 0, 0};

    i32x4 af0[8], af1[8], bf0[4], bf1[4];
    auto ldA = [&](i32x4* af, int buf, int mh) {
        const signed char* base = lds + buf * 65536;
        #pragma unroll
        for (int fm = 0; fm < 4; ++fm) {
            const int ro = (wm + mh * 64 + fm * 16 + l15) * 128;
            #pragma unroll
            for (int ks = 0; ks < 2; ++ks)
                af[fm * 2 + ks] = *(const i32x4*)(base + ro + (((ks * 4 + qg) ^ swz) << 4));
        }
    };
    auto ldB = [&](i32x4* bf, int buf, int nh) {
        const signed char* base = lds + buf * 65536 + 32768;
        #pragma unroll
        for (int fn = 0; fn < 2; ++fn) {
            const int ro = (wn + nh * 32 + fn * 16 + l15) * 128;
            #pragma unroll
            for (int ks = 0; ks < 2; ++ks)
                bf[fn * 2 + ks] = *(const i32x4*)(base + ro + (((ks * 4 + qg) ^ swz) << 4));
        }
    };
    auto mma = [&](const i32x4* af, const i32x4* bf, int mh, int nh) {
        #pragma unroll
        for (int ks = 0; ks < 2; ++ks)
            #pragma unroll
            for (int fm = 0; fm < 4; ++fm)
                #pragma unroll
                for (int fn = 0; fn < 2; ++fn)
                    acc[mh * 4 + fm][nh * 2 + fn] = __builtin_amdgcn_mfma_i32_16x16x64_i8(
                        af[fm * 2 + ks], bf[fn * 2 + ks], acc[mh * 4 + fm][nh * 2 + fn], 0, 0, 0);
    };

    // ---- prologue: buf0 complete (k0), buf1 first 3 regions (k1) ----
    stageB(0, 0, 0); stageB(0, 1, 0); stageA(0, 0, 0); stageA(0, 1, 0);
    stageB(1, 0, 1); stageB(1, 1, 1); stageA(1, 0, 1);
    VM6();   // land buf0's 4 stage-ops; leave last 3 in flight (steady pre-G4)
    BAR();

    // ---- main loop: 16 iters x 2 K-tiles ----
    for (int t = 0; t < 16; ++t) {
        const int k1 = 2 * t + 1;          // buf1 tile this iter
        const int k2 = (2 * t + 2) & 31;   // wrap: harmless garbage stage
        const int k3 = (2 * t + 3) & 31;

        // p1
        ldB(bf0, 0, 0); ldA(af0, 0, 0); stageA(1, 1, k1);
        BAR(); LGKM0(); PRIO1(); mma(af0, bf0, 0, 0); PRIO0(); BAR();
        // p2
        ldB(bf1, 0, 1); ldA(af1, 0, 1); stageB(0, 0, k2);
        BAR(); LGKM0(); PRIO1(); mma(af0, bf1, 0, 1); PRIO0(); BAR();
        // p3
        stageB(0, 1, k2);
        BAR(); LGKM0(); PRIO1(); mma(af1, bf1, 1, 1); PRIO0(); BAR();
        // p4 | GATE
        stageA(0, 0, k2);
        BAR(); LGKM0(); PRIO1(); mma(af1, bf0, 1, 0); PRIO0();
        VM6();
        BAR();
        // p5
        ldB(bf0, 1, 0); ldA(af0, 1, 0); stageA(0, 1, k2);
        BAR(); LGKM0(); PRIO1(); mma(af0, bf0, 0, 0); PRIO0(); BAR();
        // p6
        ldB(bf1, 1, 1); ldA(af1, 1, 1); stageB(1, 0, k3);
        BAR(); LGKM0(); PRIO1(); mma(af0, bf1, 0, 1); PRIO0(); BAR();
        // p7
        stageB(1, 1, k3);
        BAR(); LGKM0(); PRIO1(); mma(af1, bf1, 1, 1); PRIO0(); BAR();
        // p8 | GATE
        stageA(1, 0, k3);
        BAR(); LGKM0(); PRIO1(); mma(af1, bf0, 1, 0); PRIO0();
        VM6();
        BAR();
    }
    asm volatile("s_waitcnt vmcnt(0)" ::: "memory");  // drain tail garbage stages

    // ---- epilogue: C/D frag: col=lane&15, row=(lane>>4)*4+reg ----
    const float sw = scales[0];
    const int gn0 = pn * 256 + wn + l15;
    const int rb  = (lane >> 4) * 4;
    #pragma unroll
    for (int mi = 0; mi < 8; ++mi) {
        const int rowoff = (mi >> 2) * 64 + (mi & 3) * 16;
        #pragma unroll
        for (int r = 0; r < 4; ++r) {
            const int gm = pm * 256 + wm + rowoff + rb + r;
            const float s = sx[gm] * sw;
            float* crow = C + (size_t)gm * N_DIM + gn0;
            #pragma unroll
            for (int ni = 0; ni < 4; ++ni)
                crow[(ni >> 1) * 32 + (ni & 1) * 16] = (float)acc[mi][ni][r] * s;
        }
    }
}

extern "C" void kernel_launch(void* const* d_in, const int* in_sizes, int n_in,
                              void* d_out, int out_size, void* d_ws, size_t ws_size,
                              hipStream_t stream) {
    const float* x = (const float*)d_in[0];   // (2,2048,4096) f32
    const float* w = (const float*)d_in[1];   // (16384,4096) f32
    float* out = (float*)d_out;               // (2,2048,16384) f32
    char* ws = (char*)d_ws;

    float*  scales = (float*)(ws);                     // 2 floats
    double* part   = (double*)(ws + 1024);             // 2048 doubles
    float*  sx     = (float*)(ws + 32 * 1024);         // 4096 floats
    signed char* xq = (signed char*)(ws + 64 * 1024);  // 16 MiB
    signed char* wq = xq + (size_t)M_ROWS * K_DIM;     // 64 MiB

    k_abs_partial<<<2048, 256, 0, stream>>>((const float4*)w, part);
    k_abs_final<<<1, 256, 0, stream>>>(part, scales);
    k_wquant<<<8192, 256, 0, stream>>>((const float4*)w, scales, (char4*)wq);
    k_xquant<<<M_ROWS, 256, 0, stream>>>((const float4*)x, (char4*)xq, sx);
    k_gemm8<<<(M_ROWS / 256) * (N_DIM / 256), 512, 0, stream>>>(xq, wq, sx, scales, out);
}

// Round 6
// 405.280 us; speedup vs baseline: 1.3401x; 1.3401x over previous
//
#include <hip/hip_runtime.h>

// BitLinear: out[b,t,o] = scale_x[b,t] * scale_w * sum_d qx[b,t,d] * tw[o,d]
// qx = clip(round(127*x/(max|x|row + eps)), -128, 127)   (int8, exact)
// tw = clip(round(w/(mean|W| + eps)), -1, 1)             (ternary, exact)
// Integer GEMM via mfma_i32_16x16x64_i8, fp32 dequant epilogue.
// R6: R5 with the gate-phase race fixed. R5's bug: rd@end at p4/p8 sat
// between VM6 and BAR — vmcnt is PER-WAVE, so reads of rows staged by
// OTHER waves need the barrier (all waves past their VM6) first. Fix:
// gate reads moved to the start of the following phase (after the BAR).
// 6/8 phases keep read-ahead; p1/p5 use phase-start reads (R2-style).

#define M_ROWS 4096   // B*T
#define K_DIM  4096   // D_IN
#define N_DIM  16384  // D_OUT
#define W_ELEMS (N_DIM * K_DIM)          // 67108864
#define EPSF 1e-8f

using i32x4 = __attribute__((ext_vector_type(4))) int;

// ---------- kernel 1: |W| partial sums (deterministic) ----------
__global__ void k_abs_partial(const float4* __restrict__ w4,
                              double* __restrict__ part) {
    const int tid = threadIdx.x;
    int idx = blockIdx.x * 256 + tid;
    double s = 0.0;
    #pragma unroll 4
    for (int it = 0; it < 32; ++it) {
        float4 v = w4[idx + it * (2048 * 256)];
        s += (double)fabsf(v.x) + (double)fabsf(v.y)
           + (double)fabsf(v.z) + (double)fabsf(v.w);
    }
    __shared__ double red[256];
    red[tid] = s;
    __syncthreads();
    for (int o = 128; o > 0; o >>= 1) {
        if (tid < o) red[tid] += red[tid + o];
        __syncthreads();
    }
    if (tid == 0) part[blockIdx.x] = red[0];
}

__global__ void k_abs_final(const double* __restrict__ part,
                            float* __restrict__ scales) {
    const int tid = threadIdx.x;
    double s = 0.0;
    #pragma unroll
    for (int k = 0; k < 8; ++k) s += part[tid + k * 256];
    __shared__ double red[256];
    red[tid] = s;
    __syncthreads();
    for (int o = 128; o > 0; o >>= 1) {
        if (tid < o) red[tid] += red[tid + o];
        __syncthreads();
    }
    if (tid == 0) {
        float sw = (float)(red[0] / (double)W_ELEMS);
        scales[0] = sw;
        scales[1] = sw + EPSF;
    }
}

// ---------- kernel 2: ternary weight quant ----------
__global__ void k_wquant(const float4* __restrict__ w4,
                         const float* __restrict__ scales,
                         char4* __restrict__ wq4) {
    const float seps = scales[1];
    int idx = blockIdx.x * 256 + threadIdx.x;
    const int stride = 8192 * 256;
    #pragma unroll
    for (int it = 0; it < 8; ++it) {
        int i = idx + it * stride;
        float4 v = w4[i];
        char4 q;
        q.x = (signed char)(int)fminf(fmaxf(rintf(v.x / seps), -1.0f), 1.0f);
        q.y = (signed char)(int)fminf(fmaxf(rintf(v.y / seps), -1.0f), 1.0f);
        q.z = (signed char)(int)fminf(fmaxf(rintf(v.z / seps), -1.0f), 1.0f);
        q.w = (signed char)(int)fminf(fmaxf(rintf(v.w / seps), -1.0f), 1.0f);
        wq4[i] = q;
    }
}

// ---------- kernel 3: per-token int8 activation quant ----------
__global__ void k_xquant(const float4* __restrict__ x4,
                         char4* __restrict__ xq4,
                         float* __restrict__ sx) {
    const int row = blockIdx.x, tid = threadIdx.x;
    const float4* xr = x4 + (size_t)row * (K_DIM / 4);
    float4 v[4];
    float m = 0.0f;
    #pragma unroll
    for (int j = 0; j < 4; ++j) {
        v[j] = xr[tid + j * 256];
        m = fmaxf(m, fmaxf(fmaxf(fabsf(v[j].x), fabsf(v[j].y)),
                           fmaxf(fabsf(v[j].z), fabsf(v[j].w))));
    }
    __shared__ float red[256];
    red[tid] = m;
    __syncthreads();
    for (int o = 128; o > 0; o >>= 1) {
        if (tid < o) red[tid] = fmaxf(red[tid], red[tid + o]);
        __syncthreads();
    }
    const float gamma = red[0];
    const float ge = gamma + EPSF;
    char4* out = xq4 + (size_t)row * (K_DIM / 4);
    #pragma unroll
    for (int j = 0; j < 4; ++j) {
        char4 q;
        q.x = (signed char)(int)fminf(fmaxf(rintf(127.0f * v[j].x / ge), -128.0f), 127.0f);
        q.y = (signed char)(int)fminf(fmaxf(rintf(127.0f * v[j].y / ge), -128.0f), 127.0f);
        q.z = (signed char)(int)fminf(fmaxf(rintf(127.0f * v[j].z / ge), -128.0f), 127.0f);
        q.w = (signed char)(int)fminf(fmaxf(rintf(127.0f * v[j].w / ge), -128.0f), 127.0f);
        out[tid + j * 256] = q;
    }
    if (tid == 0) sx[row] = gamma / 127.0f;
}

// ---------- kernel 4: int8 GEMM, 256x256 tile, 8-phase, read-ahead ----------
__device__ __forceinline__ void gload16(const signed char* g, signed char* l) {
    __builtin_amdgcn_global_load_lds(
        (const __attribute__((address_space(1))) void*)g,
        (__attribute__((address_space(3))) void*)l, 16, 0, 0);
}

#define BAR()   __builtin_amdgcn_s_barrier()
#define VM6()   asm volatile("s_waitcnt vmcnt(6)" ::: "memory")
#define PRIO1() __builtin_amdgcn_s_setprio(1)
#define PRIO0() __builtin_amdgcn_s_setprio(0)
#define SCHED0() __builtin_amdgcn_sched_barrier(0)

// Geometry: BM=BN=256, BK=128 i8, 8 waves (2M x 4N), per-wave 128x64 out.
// LDS 128 KiB: 2 dbuf x (A 32K + B 32K), [256 rows][128 B], chunk-XOR swizzle
// LDS[row][c] = G[row][c ^ (row&7)] via pre-swizzled global source (rule #21).
//
// Stage schedule = R2's (HW-verified):
//   p1: stg B1.nh0(k1)   p2: stg A0.mh0(k2)   p3: stg B0.nh1(k2)
//   p4: stg A0.mh1(k2)   p5: stg B0.nh0(k2)   p6: stg A1.mh0(k3)
//   p7: stg B1.nh1(k3)   p8: stg A1.mh1(k3)
// MFMA quadrants: p1/p5 (0,0), p2/p6 (0,1), p3/p7 (1,1), p4/p8 (1,0).
// Fragment reads:
//   p1 START: af<-A0.mh0, bf<-B0.nh0 (after p8's gate BAR — cross-wave safe)
//   p1e: bf<-B0.nh1   p2e: af<-A0.mh1   p3e: bf<-B0.nh0
//   p5 START: af<-A1.mh0, bf<-B1.nh0 (after p4's gate BAR)
//   p5e: bf<-B1.nh1   p6e: af<-A1.mh1   p7e: bf<-B1.nh0
// Audited: no read/stage same-region collision within a phase; every stage
// issues >=1 barrier after its region's last read is drained. Gates:
// outstanding=14 at both VM6s; drained 8 = exactly the buffer read next;
// reads of that buffer occur only AFTER the gate barrier.
__global__ __launch_bounds__(512, 2)
void k_gemm8(const signed char* __restrict__ Aq,   // [4096][4096]  (M x K)
             const signed char* __restrict__ Bq,   // [16384][4096] (N x K)
             const float* __restrict__ sx,
             const float* __restrict__ scales,
             float* __restrict__ C) {
    __shared__ __align__(16) signed char lds[131072];

    const int tid  = threadIdx.x;
    const int lane = tid & 63;
    const int wid  = tid >> 6;
    const int l15  = lane & 15;
    const int qg   = lane >> 4;
    const int swz  = l15 & 7;

    // XCD-bijective swizzle (nwg=1024 % 8 == 0) + supergroup-of-8-pm mapping
    const int bid = blockIdx.x;
    const int wg  = (bid & 7) * 128 + (bid >> 3);
    const int gidx   = wg >> 9;
    const int within = wg & 511;
    const int pm = gidx * 8 + (within & 7);   // [0,16)
    const int pn = within >> 3;               // [0,64)

    const int wm = (wid >> 2) * 128;
    const int wn = (wid & 3) * 64;

    // staging: per-lane pre-swizzled source offset (lane l covers row r0+(l>>3),
    // chunk l&7 -> source chunk (l&7)^(l>>3))
    const int l3 = lane >> 3, l7 = lane & 7;
    const int lane_off = l3 * K_DIM + ((l7 ^ l3) << 4);
    const signed char* Asrc = Aq + (size_t)(pm * 256) * K_DIM + lane_off;
    const signed char* Bsrc = Bq + (size_t)(pn * 256) * K_DIM + lane_off;
    const int ar0 = wid * 8;
    const int br0 = (wid >> 2) * 64 + (wid & 3) * 8;

    auto stageA = [&](int buf, int mh, int kt) {
        const int r0 = mh * 64 + ar0;
        const signed char* s = Asrc + (size_t)r0 * K_DIM + kt * 128;
        signed char* d = lds + buf * 65536 + r0 * 128;
        gload16(s, d);
        gload16(s + (size_t)128 * K_DIM, d + 128 * 128);
    };
    auto stageB = [&](int buf, int nh, int kt) {
        const int r0 = nh * 32 + br0;
        const signed char* s = Bsrc + (size_t)r0 * K_DIM + kt * 128;
        signed char* d = lds + buf * 65536 + 32768 + r0 * 128;
        gload16(s, d);
        gload16(s + (size_t)128 * K_DIM, d + 128 * 128);
    };

    i32x4 acc[8][4];
    #pragma unroll
    for (int a = 0; a < 8; ++a)
        #pragma unroll
        for (int b = 0; b < 4; ++b)
            acc[a][b] = (i32x4){0, 0, 0, 0};

    i32x4 af[8], bf[4];
    auto ldA = [&](int buf, int mh) {
        const signed char* base = lds + buf * 65536;
        #pragma unroll
        for (int fm = 0; fm < 4; ++fm) {
            const int ro = (wm + mh * 64 + fm * 16 + l15) * 128;
            #pragma unroll
            for (int ks = 0; ks < 2; ++ks)
                af[fm * 2 + ks] = *(const i32x4*)(base + ro + (((ks * 4 + qg) ^ swz) << 4));
        }
    };
    auto ldB = [&](int buf, int nh) {
        const signed char* base = lds + buf * 65536 + 32768;
        #pragma unroll
        for (int fn = 0; fn < 2; ++fn) {
            const int ro = (wn + nh * 32 + fn * 16 + l15) * 128;
            #pragma unroll
            for (int ks = 0; ks < 2; ++ks)
                bf[fn * 2 + ks] = *(const i32x4*)(base + ro + (((ks * 4 + qg) ^ swz) << 4));
        }
    };
    auto mma = [&](int mh, int nh) {
        #pragma unroll
        for (int ks = 0; ks < 2; ++ks)
            #pragma unroll
            for (int fm = 0; fm < 4; ++fm)
                #pragma unroll
                for (int fn = 0; fn < 2; ++fn)
                    acc[mh * 4 + fm][nh * 2 + fn] = __builtin_amdgcn_mfma_i32_16x16x64_i8(
                        af[fm * 2 + ks], bf[fn * 2 + ks], acc[mh * 4 + fm][nh * 2 + fn], 0, 0, 0);
    };

    // ---- prologue (R2's): buf0 complete (k0); buf1 {A1.mh0,B1.nh1,A1.mh1} (k1) ----
    stageB(0, 0, 0); stageB(0, 1, 0); stageA(0, 0, 0); stageA(0, 1, 0);
    stageA(1, 0, 1); stageB(1, 1, 1); stageA(1, 1, 1);
    VM6();   // 14 outstanding -> drain 8 = buf0 complete; buf1's 6 in flight
    BAR();

    // ---- main loop: 16 iters x 2 K-tiles ----
    for (int t = 0; t < 16; ++t) {
        const int k1 = 2 * t + 1;          // buf1 tile this iter
        const int k2 = (2 * t + 2) & 31;   // wrap: harmless garbage stage
        const int k3 = (2 * t + 3) & 31;

        // p1: mma(0,0) buf0 — reads at phase start (after p8's gate BAR)
        ldA(0, 0); ldB(0, 0);
        stageB(1, 0, k1);
        BAR(); PRIO1(); mma(0, 0); PRIO0(); SCHED0();
        ldB(0, 1); SCHED0();
        BAR();
        // p2: mma(0,1) buf0
        stageA(0, 0, k2);
        BAR(); PRIO1(); mma(0, 1); PRIO0(); SCHED0();
        ldA(0, 1); SCHED0();
        BAR();
        // p3: mma(1,1) buf0
        stageB(0, 1, k2);
        BAR(); PRIO1(); mma(1, 1); PRIO0(); SCHED0();
        ldB(0, 0); SCHED0();
        BAR();
        // p4: mma(1,0) buf0 | GATE -> buf1 (k1) readable after BAR
        stageA(0, 1, k2);
        BAR(); PRIO1(); mma(1, 0); PRIO0(); SCHED0();
        VM6();
        BAR();
        // p5: mma(0,0) buf1 — reads at phase start (after p4's gate BAR)
        ldA(1, 0); ldB(1, 0);
        stageB(0, 0, k2);
        BAR(); PRIO1(); mma(0, 0); PRIO0(); SCHED0();
        ldB(1, 1); SCHED0();
        BAR();
        // p6: mma(0,1) buf1
        stageA(1, 0, k3);
        BAR(); PRIO1(); mma(0, 1); PRIO0(); SCHED0();
        ldA(1, 1); SCHED0();
        BAR();
        // p7: mma(1,1) buf1
        stageB(1, 1, k3);
        BAR(); PRIO1(); mma(1, 1); PRIO0(); SCHED0();
        ldB(1, 0); SCHED0();
        BAR();
        // p8: mma(1,0) buf1 | GATE -> buf0 (k2) readable after BAR
        stageA(1, 1, k3);
        BAR(); PRIO1(); mma(1, 0); PRIO0(); SCHED0();
        VM6();
        BAR();
    }
    asm volatile("s_waitcnt vmcnt(0)" ::: "memory");  // drain tail garbage stages

    // ---- epilogue: C/D frag: col=lane&15, row=(lane>>4)*4+reg ----
    const float sw = scales[0];
    const int gn0 = pn * 256 + wn + l15;
    const int rb  = (lane >> 4) * 4;
    #pragma unroll
    for (int mi = 0; mi < 8; ++mi) {
        const int rowoff = (mi >> 2) * 64 + (mi & 3) * 16;
        #pragma unroll
        for (int r = 0; r < 4; ++r) {
            const int gm = pm * 256 + wm + rowoff + rb + r;
            const float s = sx[gm] * sw;
            float* crow = C + (size_t)gm * N_DIM + gn0;
            #pragma unroll
            for (int ni = 0; ni < 4; ++ni)
                crow[(ni >> 1) * 32 + (ni & 1) * 16] = (float)acc[mi][ni][r] * s;
        }
    }
}

extern "C" void kernel_launch(void* const* d_in, const int* in_sizes, int n_in,
                              void* d_out, int out_size, void* d_ws, size_t ws_size,
                              hipStream_t stream) {
    const float* x = (const float*)d_in[0];   // (2,2048,4096) f32
    const float* w = (const float*)d_in[1];   // (16384,4096) f32
    float* out = (float*)d_out;               // (2,2048,16384) f32
    char* ws = (char*)d_ws;

    float*  scales = (float*)(ws);                     // 2 floats
    double* part   = (double*)(ws + 1024);             // 2048 doubles
    float*  sx     = (float*)(ws + 32 * 1024);         // 4096 floats
    signed char* xq = (signed char*)(ws + 64 * 1024);  // 16 MiB
    signed char* wq = xq + (size_t)M_ROWS * K_DIM;     // 64 MiB

    k_abs_partial<<<2048, 256, 0, stream>>>((const float4*)w, part);
    k_abs_final<<<1, 256, 0, stream>>>(part, scales);
    k_wquant<<<8192, 256, 0, stream>>>((const float4*)w, scales, (char4*)wq);
    k_xquant<<<M_ROWS, 256, 0, stream>>>((const float4*)x, (char4*)xq, sx);
    k_gemm8<<<(M_ROWS / 256) * (N_DIM / 256), 512, 0, stream>>>(xq, wq, sx, scales, out);
}